// Round 4
// baseline (8680.104 us; speedup 1.0000x reference)
//
#include <hip/hip_runtime.h>
#include <hip/hip_bf16.h>

typedef unsigned short u16;
typedef float f32x4 __attribute__((ext_vector_type(4)));
typedef short s16x8 __attribute__((ext_vector_type(8)));

// B=4, C=D=60, N=25, H=W=96; HW=9216, S=230400, HW2=2304, S2=57600, DN=1500 (pad 1536)
// Batch-serial pipeline: all per-batch buffers fit in ~225 MB of workspace.
// PF_b rows (180): 0..59 spa_q | 60..119 ang_v | 120..179 fre_v
// CAT_b (bf16): slot = qc*25+n (qc 0..179), inner hw.

__device__ __forceinline__ float b2f(u16 u) {
  union { unsigned int i; float f; } v; v.i = ((unsigned int)u) << 16; return v.f;
}
__device__ __forceinline__ u16 f2b(float f) {
  union { float f; unsigned int i; } v; v.f = f;
  unsigned int i = v.i + 0x7FFFu + ((v.i >> 16) & 1u);  // RNE
  return (u16)(i >> 16);
}

// ---------------- fallback (ws too small): out = x ----------------
__global__ void fallback_copy(const float* __restrict__ x, float* __restrict__ out, size_t n) {
  size_t i = (size_t)blockIdx.x * 256 + threadIdx.x;
  size_t st = (size_t)gridDim.x * 256;
  for (; i < n; i += st) out[i] = x[i];
}

// ---------------- cast x_b -> bf16 (1536,9216), pad rows zeroed ----------------
__global__ __launch_bounds__(256) void cast_x(const float* __restrict__ xb, u16* __restrict__ Xb) {
  size_t e = ((size_t)blockIdx.x * 256 + threadIdx.x) * 4;   // < 14155776
  ushort4 o;
  if (e < 13824000) {
    float4 v = *(const float4*)(xb + e);
    o.x = f2b(v.x); o.y = f2b(v.y); o.z = f2b(v.z); o.w = f2b(v.w);
  } else { o.x = 0; o.y = 0; o.z = 0; o.w = 0; }
  *(ushort4*)(Xb + e) = o;
}

// ---------------- projections (per batch) ----------------
__global__ __launch_bounds__(256) void proj_full(const float* __restrict__ xb,
    const float* __restrict__ Wq, const float* __restrict__ Wang,
    const float* __restrict__ Wfre, u16* __restrict__ PF) {
  int s = blockIdx.x * 256 + threadIdx.x;      // 0..230399
  const float* xs = xb + s;
  float xr[60];
#pragma unroll
  for (int c = 0; c < 60; ++c) xr[c] = xs[(size_t)c * 230400];
  u16* ob = PF + s;
  for (int r = 0; r < 60; ++r) {                 // spa_q
    const float* w = Wq + r * 60; float a = 0.f;
#pragma unroll
    for (int c = 0; c < 60; ++c) a += w[c] * xr[c];
    ob[(size_t)r * 230400] = f2b(a);
  }
  for (int r = 0; r < 60; ++r) {                 // ang_v = w_ang rows 120..179
    const float* w = Wang + (120 + r) * 60; float a = 0.f;
#pragma unroll
    for (int c = 0; c < 60; ++c) a += w[c] * xr[c];
    ob[(size_t)(60 + r) * 230400] = f2b(a);
  }
  for (int r = 0; r < 60; ++r) {                 // fre_v = w_fre rows 120..179
    const float* w = Wfre + (120 + r) * 60; float a = 0.f;
#pragma unroll
    for (int c = 0; c < 60; ++c) a += w[c] * xr[c];
    ob[(size_t)(120 + r) * 230400] = f2b(a);
  }
}

__global__ __launch_bounds__(256) void proj_sub(const float* __restrict__ xb,
    const float* __restrict__ Wkv, u16* __restrict__ PS) {
  int s2 = blockIdx.x * 256 + threadIdx.x;     // 0..57599
  int nn = s2 / 2304; int rem = s2 - nn * 2304;
  int hy = rem / 48;  int hx = rem - hy * 48;
  const float* xs = xb + (size_t)nn * 9216 + hy * 192 + hx * 2;
  float xr[60];
#pragma unroll
  for (int c = 0; c < 60; ++c) xr[c] = xs[(size_t)c * 230400];
  u16* ob = PS + s2;
  for (int r = 0; r < 120; ++r) {
    const float* w = Wkv + r * 60; float a = 0.f;
#pragma unroll
    for (int c = 0; c < 60; ++c) a += w[c] * xr[c];
    ob[(size_t)r * 57600] = f2b(a);
  }
}

// ---------------- normalize (over f=1500) + transpose to (site, 1536) ----------------
__global__ __launch_bounds__(256) void norm_transpose(const u16* __restrict__ inb,
    u16* __restrict__ outb, int S) {
  __shared__ float red[256];
  __shared__ float rinv[64];
  __shared__ float Ts[64 * 65];
  int s0 = blockIdx.x * 64;
  int t = threadIdx.x; int sl = t & 63; int g = t >> 6;
  float ss = 0.f;
  for (int f = g; f < 1500; f += 4) {
    float v = b2f(inb[(size_t)f * S + s0 + sl]);
    ss += v * v;
  }
  red[t] = ss; __syncthreads();
  if (t < 64) {
    float tot = red[t] + red[t + 64] + red[t + 128] + red[t + 192];
    rinv[t] = 1.f / fmaxf(sqrtf(tot), 1e-12f);
  }
  __syncthreads();
  for (int f0 = 0; f0 < 1536; f0 += 64) {
    for (int e = t; e < 4096; e += 256) {
      int fr = e >> 6, sc = e & 63; int f = f0 + fr;
      Ts[fr * 65 + sc] = (f < 1500) ? b2f(inb[(size_t)f * S + s0 + sc]) : 0.f;
    }
    __syncthreads();
    for (int sr = g; sr < 64; sr += 4) {
      float v = Ts[sl * 65 + sr] * rinv[sr];
      outb[(size_t)(s0 + sr) * 1536 + f0 + sl] = f2b(v);
    }
    __syncthreads();
  }
}

// ---------------- bf16 MFMA GEMM: C[M,N] = A[M,K] * BT[N,K]^T (per batch) ----------------
// EPI 0: fp32 row-major. EPI 2: bf16 col-major (col*M+row), col<1500 only.
template<int M, int N, int K, int EPI>
__global__ __launch_bounds__(256) void gemm_bt(const u16* __restrict__ A,
    const u16* __restrict__ BT, void* __restrict__ C) {
  __shared__ __align__(16) u16 As[128 * 40];
  __shared__ __align__(16) u16 Bs[128 * 40];
  const int tid = threadIdx.x;
  const int bm = blockIdx.x, bn = blockIdx.y;
  const int lane = tid & 63;
  const int wv = tid >> 6;
  const int wm = (wv >> 1) * 64, wn = (wv & 1) * 64;
  const int lm = lane & 15, lq = lane >> 4;
  f32x4 z = {0.f, 0.f, 0.f, 0.f};
  f32x4 acc[4][4];
#pragma unroll
  for (int i = 0; i < 4; ++i)
#pragma unroll
    for (int j = 0; j < 4; ++j) acc[i][j] = z;

  for (int k0 = 0; k0 < K; k0 += 32) {
    __syncthreads();
#pragma unroll
    for (int r = 0; r < 4; ++r) {
      int idx = tid + (r << 8);              // 0..1023
      int row = (idx >> 2) & 127;
      int seg = idx & 3;
      if (r < 2) {
        const uint4* src = (const uint4*)(A + (size_t)(bm * 128 + row) * K + k0 + seg * 8);
        *(uint4*)&As[row * 40 + seg * 8] = *src;
      } else {
        const uint4* src = (const uint4*)(BT + (size_t)(bn * 128 + row) * K + k0 + seg * 8);
        *(uint4*)&Bs[row * 40 + seg * 8] = *src;
      }
    }
    __syncthreads();
    s16x8 af[4], bf[4];
#pragma unroll
    for (int i = 0; i < 4; ++i)
      af[i] = *(const s16x8*)&As[(wm + i * 16 + lm) * 40 + lq * 8];
#pragma unroll
    for (int j = 0; j < 4; ++j)
      bf[j] = *(const s16x8*)&Bs[(wn + j * 16 + lm) * 40 + lq * 8];
#pragma unroll
    for (int i = 0; i < 4; ++i)
#pragma unroll
      for (int j = 0; j < 4; ++j)
        acc[i][j] = __builtin_amdgcn_mfma_f32_16x16x32_bf16(af[i], bf[j], acc[i][j], 0, 0, 0);
  }

#pragma unroll
  for (int i = 0; i < 4; ++i) {
    int row0 = bm * 128 + wm + i * 16 + lq * 4;
#pragma unroll
    for (int j = 0; j < 4; ++j) {
      int col = bn * 128 + wn + j * 16 + lm;
      if (EPI == 0) {
        float* Cb = (float*)C;
#pragma unroll
        for (int r = 0; r < 4; ++r)
          Cb[(size_t)(row0 + r) * N + col] = acc[i][j][r];
      } else {
        if (col < 1500) {
          u16* Cb = (u16*)C;
          uint2 pk;
          pk.x = (unsigned int)f2b(acc[i][j][0]) | ((unsigned int)f2b(acc[i][j][1]) << 16);
          pk.y = (unsigned int)f2b(acc[i][j][2]) | ((unsigned int)f2b(acc[i][j][3]) << 16);
          *(uint2*)&Cb[(size_t)col * M + row0] = pk;
        }
      }
    }
  }
}

// ---------------- row softmax (2304 cols) fp32 -> bf16 ----------------
__global__ __launch_bounds__(256) void softmax_rows(const float* __restrict__ L,
                                                    u16* __restrict__ att) {
  size_t row = blockIdx.x;
  const float* Lr = L + row * 2304;
  u16* ar = att + row * 2304;
  int t = threadIdx.x;
  float v[9]; float mx = -1e30f;
#pragma unroll
  for (int i = 0; i < 9; ++i) { v[i] = Lr[t + i * 256]; mx = fmaxf(mx, v[i]); }
  __shared__ float red[256];
  red[t] = mx; __syncthreads();
  for (int st = 128; st > 0; st >>= 1) { if (t < st) red[t] = fmaxf(red[t], red[t + st]); __syncthreads(); }
  mx = red[0]; __syncthreads();
  float s = 0.f;
#pragma unroll
  for (int i = 0; i < 9; ++i) { v[i] = __expf(v[i] - mx); s += v[i]; }
  red[t] = s; __syncthreads();
  for (int st = 128; st > 0; st >>= 1) { if (t < st) red[t] += red[t + st]; __syncthreads(); }
  float rs = 1.f / red[0];
#pragma unroll
  for (int i = 0; i < 9; ++i) ar[t + i * 256] = f2b(v[i] * rs);
}

// ---------------- angular attention from G2 (one block per batch) ----------------
__global__ __launch_bounds__(256) void ang_small(const float* __restrict__ G,
    const float* __restrict__ Ma_g, const float* __restrict__ Mq_g,
    const float* __restrict__ Mk_g, float* __restrict__ Aatt) {
  __shared__ float Ma[3600], Mq[3600], Mk[3600];
  __shared__ float dots[625], qn[25], kn[25];
  int t = threadIdx.x;
  for (int e = t; e < 3600; e += 256) { Ma[e] = Ma_g[e]; Mq[e] = Mq_g[e]; Mk[e] = Mk_g[e]; }
  __syncthreads();
  for (int p = t; p < 675; p += 256) {
    const float* m; int ri, ci;
    if (p < 625)      { m = Ma; ri = p / 25; ci = p % 25; }
    else if (p < 650) { m = Mq; ri = p - 625; ci = ri; }
    else              { m = Mk; ri = p - 650; ci = ri; }
    float a = 0.f;
    for (int c = 0; c < 60; ++c) {
      const float* row = G + (size_t)(c * 25 + ri) * 1536 + ci;
      const float* mr = m + c * 60;
#pragma unroll 6
      for (int cp = 0; cp < 60; ++cp) a += mr[cp] * row[cp * 25];
    }
    if (p < 625) dots[p] = a;
    else if (p < 650) qn[ri] = a;
    else kn[ri] = a;
  }
  __syncthreads();
  if (t < 25) {
    float rq = 1.f / fmaxf(sqrtf(qn[t]), 1e-12f);
    float l[25], mx = -1e30f;
    for (int j = 0; j < 25; ++j) {
      float rk = 1.f / fmaxf(sqrtf(kn[j]), 1e-12f);
      l[j] = dots[t * 25 + j] * rq * rk;
      mx = fmaxf(mx, l[j]);
    }
    float s = 0.f;
    for (int j = 0; j < 25; ++j) { l[j] = __expf(l[j] - mx); s += l[j]; }
    float rs = 1.f / s;
    for (int j = 0; j < 25; ++j) Aatt[t * 25 + j] = l[j] * rs;
  }
}

// ---------------- frequency attention from G2 (one block per batch) ----------------
__global__ __launch_bounds__(256) void fre_small(const float* __restrict__ G,
    const float* __restrict__ Wfre, float* __restrict__ Fatt) {
  __shared__ float Gs[3600], T1q[3600], T1k[3600];
  __shared__ float qn[60], kn[60];
  int t = threadIdx.x;
  for (int e = t; e < 3600; e += 256) {       // Gs[c,c'] = sum_n G2[(c,n),(c',n)]
    int c = e / 60, cp = e % 60;
    const float* base = G + (size_t)(c * 25) * 1536 + cp * 25;
    float a = 0.f;
#pragma unroll
    for (int n = 0; n < 25; ++n) a += base[(size_t)n * 1537];
    Gs[e] = a;
  }
  __syncthreads();
  for (int e = t; e < 3600; e += 256) {       // T1q = Wfq*Gs, T1k = Wfk*Gs
    int u = e / 60, cp = e % 60;
    const float* wq = Wfre + u * 60;
    const float* wk = Wfre + 3600 + u * 60;
    float aq = 0.f, ak = 0.f;
    for (int c = 0; c < 60; ++c) { float g = Gs[c * 60 + cp]; aq += wq[c] * g; ak += wk[c] * g; }
    T1q[e] = aq; T1k[e] = ak;
  }
  __syncthreads();
  for (int e = t; e < 3600; e += 256) {       // dots (reuse Gs)
    int u = e / 60, v = e % 60;
    const float* wk = Wfre + 3600 + v * 60;
    float a = 0.f;
    for (int cp = 0; cp < 60; ++cp) a += T1q[u * 60 + cp] * wk[cp];
    Gs[e] = a;
  }
  for (int u = t; u < 60; u += 256) {
    const float* wq = Wfre + u * 60;
    const float* wk = Wfre + 3600 + u * 60;
    float aq = 0.f, ak = 0.f;
    for (int cp = 0; cp < 60; ++cp) { aq += T1q[u * 60 + cp] * wq[cp]; ak += T1k[u * 60 + cp] * wk[cp]; }
    qn[u] = aq; kn[u] = ak;
  }
  __syncthreads();
  if (t < 60) {
    float rq = 1.f / fmaxf(sqrtf(qn[t]), 1e-12f);
    float l[60], mx = -1e30f;
    for (int v = 0; v < 60; ++v) {
      float rk = 1.f / fmaxf(sqrtf(kn[v]), 1e-12f);
      l[v] = Gs[t * 60 + v] * rq * rk;
      mx = fmaxf(mx, l[v]);
    }
    float s = 0.f;
    for (int v = 0; v < 60; ++v) { l[v] = __expf(l[v] - mx); s += l[v]; }
    float rs = 1.f / s;
    for (int v = 0; v < 60; ++v) Fatt[t * 60 + v] = l[v] * rs;
  }
}

// ---------------- a_fea / f_fea -> CAT (bf16, per batch) ----------------
__global__ __launch_bounds__(256) void a_fea(const u16* __restrict__ PF,
    const float* __restrict__ Aatt, u16* __restrict__ CAT) {
  int hw = blockIdx.x * 256 + threadIdx.x;
  int dd = blockIdx.y;
  const u16* V = PF + ((size_t)(60 + dd)) * 230400 + hw;
  float v[25];
#pragma unroll
  for (int j = 0; j < 25; ++j) v[j] = b2f(V[(size_t)j * 9216]);
  u16* ob = CAT + (size_t)(1500 + dd * 25) * 9216 + hw;
  for (int i = 0; i < 25; ++i) {
    float a = 0.f;
#pragma unroll
    for (int j = 0; j < 25; ++j) a += Aatt[i * 25 + j] * v[j];
    ob[(size_t)i * 9216] = f2b(a);
  }
}

__global__ __launch_bounds__(256) void f_fea(const u16* __restrict__ PF,
    const float* __restrict__ Fatt, u16* __restrict__ CAT) {
  int s = blockIdx.x * 256 + threadIdx.x;
  const u16* V = PF + (size_t)120 * 230400 + s;
  float v[60];
#pragma unroll
  for (int u = 0; u < 60; ++u) v[u] = b2f(V[(size_t)u * 230400]);
  u16* ob = CAT + (size_t)27648000 + s;
  for (int u = 0; u < 60; ++u) {
    float a = 0.f;
#pragma unroll
    for (int vv = 0; vv < 60; ++vv) a += Fatt[u * 60 + vv] * v[vv];
    ob[(size_t)u * 230400] = f2b(a);
  }
}

// ---------------- precompute small weight products (once) ----------------
__global__ void precompute(const float* __restrict__ W1, const float* __restrict__ W2,
    const float* __restrict__ gamma, const float* __restrict__ beta,
    const float* __restrict__ Wang,
    float* __restrict__ Avec, float* __restrict__ Btvec,
    float* __restrict__ W1T, float* __restrict__ W2T,
    float* __restrict__ Ma, float* __restrict__ Mq, float* __restrict__ Mk) {
  int t = threadIdx.x;
  for (int e = t; e < 10800; e += 256) { int q = e / 60, j = e % 60; W1T[e] = W1[j * 180 + q]; }
  for (int e = t; e < 3600;  e += 256) { int j = e / 60, k = e % 60; W2T[e] = W2[k * 60 + j]; }
  for (int e = t; e < 3600; e += 256) {
    int c = e / 60, cp = e % 60;
    const float* Waq = Wang;            // rows 0..59
    const float* Wak = Wang + 3600;     // rows 60..119
    float ma = 0.f, mq = 0.f, mk = 0.f;
    for (int d = 0; d < 60; ++d) {
      float q = Waq[d * 60 + c], qp = Waq[d * 60 + cp];
      float k = Wak[d * 60 + c], kp = Wak[d * 60 + cp];
      ma += q * kp; mq += q * qp; mk += k * kp;
    }
    Ma[e] = ma; Mq[e] = mq; Mk[e] = mk;
  }
  if (t < 60) {
    float a = 0.f, bt = 0.f;
    for (int q = 0; q < 180; ++q) { a += gamma[q] * W1[t * 180 + q]; bt += beta[q] * W1[t * 180 + q]; }
    Avec[t] = a; Btvec[t] = bt;
  }
}

// ---------------- fused LayerNorm + MLP + residual (per batch) ----------------
__global__ __launch_bounds__(256) void fuse_ln_mlp(const u16* __restrict__ CAT,
    const float* __restrict__ xb, const float* __restrict__ gamma,
    const float* __restrict__ W1T, const float* __restrict__ W2T,
    const float* __restrict__ Avec, const float* __restrict__ Btvec,
    float* __restrict__ outb) {
  int s = blockIdx.x * 256 + threadIdx.x;
  const u16* cb = CAT + s;
  float S1[60];
#pragma unroll
  for (int j = 0; j < 60; ++j) S1[j] = 0.f;
  float sum = 0.f, sq = 0.f;
  for (int q = 0; q < 180; ++q) {
    float val = b2f(cb[(size_t)q * 230400]);
    sum += val; sq += val * val;
    float u = val * gamma[q];
    const float* w = W1T + q * 60;
#pragma unroll
    for (int j = 0; j < 60; ++j) S1[j] += u * w[j];
  }
  float mu = sum * (1.f / 180.f);
  float var = sq * (1.f / 180.f) - mu * mu;
  float inv = rsqrtf(var + 1e-5f);
  float y2[60];
#pragma unroll
  for (int k = 0; k < 60; ++k) y2[k] = 0.f;
  for (int j = 0; j < 60; ++j) {
    float y1 = inv * (S1[j] - mu * Avec[j]) + Btvec[j];
    y1 = fmaxf(y1, 0.f);
    const float* w = W2T + j * 60;
#pragma unroll
    for (int k = 0; k < 60; ++k) y2[k] += y1 * w[k];
  }
  const float* xs = xb + s;
  float* ob = outb + s;
#pragma unroll
  for (int k = 0; k < 60; ++k) ob[(size_t)k * 230400] = y2[k] + xs[(size_t)k * 230400];
}

// ---------------- launch ----------------
extern "C" void kernel_launch(void* const* d_in, const int* in_sizes, int n_in,
                              void* d_out, int out_size, void* d_ws, size_t ws_size,
                              hipStream_t stream) {
  const float* x        = (const float*)d_in[0];
  const float* w_spa_q  = (const float*)d_in[1];
  const float* w_spa_kv = (const float*)d_in[2];
  const float* w_ang    = (const float*)d_in[3];
  const float* w_fre    = (const float*)d_in[4];
  const float* ln_gamma = (const float*)d_in[5];
  const float* ln_beta  = (const float*)d_in[6];
  const float* w_mlp1   = (const float*)d_in[7];
  const float* w_mlp2   = (const float*)d_in[8];
  float* out = (float*)d_out;
  (void)in_sizes; (void)n_in; (void)out_size;

  // -------- workspace plan: three overlapping regions, peak ~224.6 MB --------
  char* ws = (char*)d_ws;
  const size_t A1 = 0;                       // U1: PF_b | PS_b
  const size_t A1_PS = 82944256;             // PF_b = 82,944,000 B
  const size_t A2 = 96934656;                // U2: G2_b -> sqn_b+skn_b -> att_b (42,467,328 B)
  const size_t A3 = 139401984;               // U3: Xb_b -> L_b fp32 -> CAT_b bf16 (84,934,656 B)
  size_t off = 224336640;                    // smalls
  auto alloc = [&](size_t bytes) -> void* {
    void* p = ws + off; off = (off + bytes + 255) & ~(size_t)255; return p;
  };
  float* Aatt  = (float*)alloc(4 * 625 * 4);    // 4 batches x 625 floats
  float* Fatt  = (float*)alloc(4 * 3600 * 4);   // 4 batches x 3600 floats  (was 1 batch: the round-3 bug)
  float* Avec  = (float*)alloc(240);
  float* Btvec = (float*)alloc(240);
  float* W1T   = (float*)alloc(43200);
  float* W2T   = (float*)alloc(14400);
  float* Ma    = (float*)alloc(14400);
  float* Mq    = (float*)alloc(14400);
  float* Mk    = (float*)alloc(14400);

  if (off > ws_size) {  // graceful fallback: out = x (diagnosable, no fault)
    fallback_copy<<<4096, 256, 0, stream>>>(x, out, (size_t)55296000);
    return;
  }

  u16*   PF  = (u16*)(ws + A1);
  u16*   PS  = (u16*)(ws + A1_PS);
  float* G2  = (float*)(ws + A2);            //  9,437,184 B
  u16*   sqn = (u16*)(ws + A2);              // 28,311,552 B
  u16*   skn = (u16*)(ws + A2 + 28311552);   //  7,077,888 B
  u16*   att = (u16*)(ws + A2);              // 42,467,328 B
  u16*   Xb  = (u16*)(ws + A3);              // 28,311,552 B
  float* L   = (float*)(ws + A3);            // 84,934,656 B
  u16*   CAT = (u16*)(ws + A3);              // 82,944,000 B

  precompute<<<1, 256, 0, stream>>>(w_mlp1, w_mlp2, ln_gamma, ln_beta, w_ang,
                                    Avec, Btvec, W1T, W2T, Ma, Mq, Mk);

  for (int b = 0; b < 4; ++b) {
    const float* xb = x + (size_t)b * 13824000;
    float* outb = out + (size_t)b * 13824000;

    // --- gram-based angular + frequency attention ---
    cast_x<<<13824, 256, 0, stream>>>(xb, Xb);
    gemm_bt<1536, 1536, 9216, 0><<<dim3(12, 12), 256, 0, stream>>>(Xb, Xb, G2);
    ang_small<<<1, 256, 0, stream>>>(G2, Ma, Mq, Mk, Aatt + b * 625);
    fre_small<<<1, 256, 0, stream>>>(G2, w_fre, Fatt + b * 3600);

    // --- projections ---
    proj_full<<<900, 256, 0, stream>>>(xb, w_spa_q, w_ang, w_fre, PF);
    proj_sub<<<225, 256, 0, stream>>>(xb, w_spa_kv, PS);

    // --- spatial attention (sqn/skn overwrite G2; Xb dead) ---
    norm_transpose<<<144, 256, 0, stream>>>(PF, sqn, 9216);
    norm_transpose<<<36, 256, 0, stream>>>(PS, skn, 2304);
    gemm_bt<9216, 2304, 1536, 0><<<dim3(72, 18), 256, 0, stream>>>(sqn, skn, L);
    softmax_rows<<<9216, 256, 0, stream>>>(L, att);   // att overwrites sqn/skn (dead)
    gemm_bt<9216, 1536, 2304, 2><<<dim3(72, 12), 256, 0, stream>>>(att, PS + 3456000, CAT);

    // --- small attention features ---
    a_fea<<<dim3(36, 60), 256, 0, stream>>>(PF, Aatt + b * 625, CAT);
    f_fea<<<900, 256, 0, stream>>>(PF, Fatt + b * 3600, CAT);

    // --- LN + MLP + residual ---
    fuse_ln_mlp<<<900, 256, 0, stream>>>(CAT, xb, ln_gamma, W1T, W2T, Avec, Btvec, outb);
  }
}